// Round 3
// baseline (15430.803 us; speedup 1.0000x reference)
//
#include <hip/hip_runtime.h>
#include <math.h>

// Problem constants (fixed by the reference)
constexpr int B_ = 4096, D_ = 1024, H_ = 4096, E_ = 8, K_ = 4096, V_ = 50257;

constexpr int THREADS = 256;
constexpr int BM = 128, BN = 128, BKs = 16;   // 8x8 microtile per thread

// ---------------- activations ----------------
template<int ACT> __device__ __forceinline__ float act_fn(float x) {
  if constexpr (ACT == 1) return fmaxf(x, 0.0f);                                    // relu
  if constexpr (ACT == 2) return 0.5f * x * (1.0f + erff(x * 0.7071067811865475f)); // exact gelu
  if constexpr (ACT == 3) return 1.0f / (1.0f + expf(-x));                          // sigmoid
  return x;
}

// ---------------- generic C = act(A @ B^T + bias) ----------------
// A[M,K] row-major, B[N,K] row-major (torch Linear weight), C[M,N].
// M % 128 == 0, K % 16 == 0 assumed; N may be ragged (adapter V=50257).
template<int ACT>
__global__ __launch_bounds__(THREADS)
void sgemm_abt(const float* __restrict__ A, const float* __restrict__ Bm,
               const float* __restrict__ bias, float* __restrict__ C,
               int M, int N, int K) {
  __shared__ float As[BKs][BM];
  __shared__ float Bs[BKs][BN];
  const int tid = threadIdx.x;
  const int m0 = blockIdx.x * BM;
  const int n0 = blockIdx.y * BN;
  const int tx = tid & 15, ty = tid >> 4;
  const int lr = tid >> 2;         // 0..63
  const int lc = (tid & 3) * 4;    // 0,4,8,12
  float acc[8][8] = {};
  for (int k0 = 0; k0 < K; k0 += BKs) {
#pragma unroll
    for (int p = 0; p < 2; ++p) {
      const int r = lr + p * 64;
      const float4 v = *(const float4*)(A + (size_t)(m0 + r) * K + k0 + lc);
      As[lc + 0][r] = v.x; As[lc + 1][r] = v.y; As[lc + 2][r] = v.z; As[lc + 3][r] = v.w;
    }
#pragma unroll
    for (int p = 0; p < 2; ++p) {
      const int r = lr + p * 64;
      float4 v = make_float4(0.f, 0.f, 0.f, 0.f);
      if (n0 + r < N) v = *(const float4*)(Bm + (size_t)(n0 + r) * K + k0 + lc);
      Bs[lc + 0][r] = v.x; Bs[lc + 1][r] = v.y; Bs[lc + 2][r] = v.z; Bs[lc + 3][r] = v.w;
    }
    __syncthreads();
#pragma unroll
    for (int kk = 0; kk < BKs; ++kk) {
      float a[8], b[8];
      *(float4*)&a[0] = *(const float4*)&As[kk][ty * 8];
      *(float4*)&a[4] = *(const float4*)&As[kk][ty * 8 + 4];
      *(float4*)&b[0] = *(const float4*)&Bs[kk][tx * 8];
      *(float4*)&b[4] = *(const float4*)&Bs[kk][tx * 8 + 4];
#pragma unroll
      for (int i = 0; i < 8; ++i)
#pragma unroll
        for (int j = 0; j < 8; ++j)
          acc[i][j] = fmaf(a[i], b[j], acc[i][j]);
    }
    __syncthreads();
  }
  const bool hasb = (bias != nullptr);
#pragma unroll
  for (int i = 0; i < 8; ++i) {
    const int row = m0 + ty * 8 + i;
#pragma unroll
    for (int j = 0; j < 8; ++j) {
      const int col = n0 + tx * 8 + j;
      if (col < N) {
        float v = acc[i][j];
        if (hasb) v += bias[col];
        C[(size_t)row * N + col] = act_fn<ACT>(v);
      }
    }
  }
}

// ---------------- C += A @ B  (attn @ values, added into x) ----------------
// A[M,K] row-major, B[K,N] row-major. All dims multiples of tile here.
__global__ __launch_bounds__(THREADS)
void sgemm_ab_add(const float* __restrict__ A, const float* __restrict__ Bm,
                  float* __restrict__ C, int M, int N, int K) {
  __shared__ float As[BKs][BM];
  __shared__ float Bs[BKs][BN];
  const int tid = threadIdx.x;
  const int m0 = blockIdx.x * BM;
  const int n0 = blockIdx.y * BN;
  const int tx = tid & 15, ty = tid >> 4;
  const int lr = tid >> 2, lc = (tid & 3) * 4;
  float acc[8][8] = {};
  for (int k0 = 0; k0 < K; k0 += BKs) {
#pragma unroll
    for (int p = 0; p < 2; ++p) {
      const int r = lr + p * 64;
      const float4 v = *(const float4*)(A + (size_t)(m0 + r) * K + k0 + lc);
      As[lc + 0][r] = v.x; As[lc + 1][r] = v.y; As[lc + 2][r] = v.z; As[lc + 3][r] = v.w;
    }
#pragma unroll
    for (int p = 0; p < 2; ++p) {
      const int idx = tid + p * 256;
      const int kk = idx >> 5;            // 0..15
      const int c4 = (idx & 31) * 4;      // 0..124
      *(float4*)&Bs[kk][c4] = *(const float4*)(Bm + (size_t)(k0 + kk) * N + n0 + c4);
    }
    __syncthreads();
#pragma unroll
    for (int kk = 0; kk < BKs; ++kk) {
      float a[8], b[8];
      *(float4*)&a[0] = *(const float4*)&As[kk][ty * 8];
      *(float4*)&a[4] = *(const float4*)&As[kk][ty * 8 + 4];
      *(float4*)&b[0] = *(const float4*)&Bs[kk][tx * 8];
      *(float4*)&b[4] = *(const float4*)&Bs[kk][tx * 8 + 4];
#pragma unroll
      for (int i = 0; i < 8; ++i)
#pragma unroll
        for (int j = 0; j < 8; ++j)
          acc[i][j] = fmaf(a[i], b[j], acc[i][j]);
    }
    __syncthreads();
  }
#pragma unroll
  for (int i = 0; i < 8; ++i) {
    const int row = m0 + ty * 8 + i;
#pragma unroll
    for (int j = 0; j < 8; ++j) {
      const int col = n0 + tx * 8 + j;
      C[(size_t)row * N + col] += acc[i][j];
    }
  }
}

// ---------------- MoE: gate + softmax + top2 ----------------
__global__ __launch_bounds__(64)
void gate_topk(const float* __restrict__ Z, const float* __restrict__ gw,
               const float* __restrict__ gb, int* __restrict__ topk_idx,
               float* __restrict__ topk_w, int* __restrict__ counts) {
  const int b = blockIdx.x, lane = threadIdx.x;
  const float* zr = Z + (size_t)b * D_;
  float l[E_];
#pragma unroll
  for (int e = 0; e < E_; ++e) {
    float s = 0.f;
    for (int d = lane; d < D_; d += 64) s += zr[d] * gw[e * D_ + d];
#pragma unroll
    for (int o = 32; o > 0; o >>= 1) s += __shfl_down(s, o);
    l[e] = s;
  }
  if (lane == 0) {
    float mx = -3.4e38f;
#pragma unroll
    for (int e = 0; e < E_; ++e) { l[e] += gb[e]; mx = fmaxf(mx, l[e]); }
    float w[E_]; float sum = 0.f;
#pragma unroll
    for (int e = 0; e < E_; ++e) { w[e] = expf(l[e] - mx); sum += w[e]; }
    const float inv = 1.f / sum;
#pragma unroll
    for (int e = 0; e < E_; ++e) w[e] *= inv;
    int i0 = 0;
#pragma unroll
    for (int e = 1; e < E_; ++e) if (w[e] > w[i0]) i0 = e;   // stable: earliest on tie
    int i1 = (i0 == 0) ? 1 : 0;
#pragma unroll
    for (int e = 0; e < E_; ++e) if (e != i0 && w[e] > w[i1]) i1 = e;
    topk_idx[2 * b] = i0; topk_idx[2 * b + 1] = i1;
    topk_w[2 * b] = w[i0]; topk_w[2 * b + 1] = w[i1];
    atomicAdd(&counts[i0], 1); atomicAdd(&counts[i1], 1);
  }
}

__global__ void zero8(int* c) { if (threadIdx.x < 8) c[threadIdx.x] = 0; }

__global__ void scan8(const int* __restrict__ counts, int* __restrict__ offs,
                      int* __restrict__ curs) {
  if (threadIdx.x == 0 && blockIdx.x == 0) {
    int a = 0;
    for (int e = 0; e < E_; ++e) { offs[e] = a; curs[e] = a; a += counts[e]; }
  }
}

__global__ void bin_fill(const int* __restrict__ topk_idx, int* __restrict__ curs,
                         int* __restrict__ rows, int* __restrict__ slotpos) {
  const int t = blockIdx.x * blockDim.x + threadIdx.x;
  if (t < 2 * B_) {
    const int e = topk_idx[t];
    const int pos = atomicAdd(&curs[e], 1);
    rows[pos] = t >> 1;
    slotpos[t] = pos;
  }
}

// ---------------- MoE expert fc1: Hb[slot,:] = relu(z[rows[slot]] @ ew1[e]^T + eb1[e]) ----------------
__global__ __launch_bounds__(THREADS)
void moe_fc1(const float* __restrict__ Z, const float* __restrict__ ew1,
             const float* __restrict__ eb1, float* __restrict__ Hb,
             const int* __restrict__ rows, const int* __restrict__ offs,
             const int* __restrict__ counts) {
  __shared__ float As[BKs][BM];
  __shared__ float Bs[BKs][BN];
  const int e = blockIdx.x >> 5;
  const int me = (blockIdx.x & 31) * BM;
  const int cnt = counts[e], off = offs[e];
  if (me >= cnt) return;
  const int n0 = blockIdx.y * BN;
  const float* Bm = ew1 + (size_t)e * H_ * D_;
  const float* bias = eb1 + (size_t)e * H_;
  const int tid = threadIdx.x;
  const int tx = tid & 15, ty = tid >> 4;
  const int lr = tid >> 2, lc = (tid & 3) * 4;
  int gr[2];
#pragma unroll
  for (int p = 0; p < 2; ++p) {
    const int r = me + lr + p * 64;
    gr[p] = (r < cnt) ? rows[off + r] : 0;
  }
  float acc[8][8] = {};
  for (int k0 = 0; k0 < D_; k0 += BKs) {
#pragma unroll
    for (int p = 0; p < 2; ++p) {
      const int r = lr + p * 64;
      const float4 v = *(const float4*)(Z + (size_t)gr[p] * D_ + k0 + lc);
      As[lc + 0][r] = v.x; As[lc + 1][r] = v.y; As[lc + 2][r] = v.z; As[lc + 3][r] = v.w;
    }
#pragma unroll
    for (int p = 0; p < 2; ++p) {
      const int r = lr + p * 64;
      const float4 v = *(const float4*)(Bm + (size_t)(n0 + r) * D_ + k0 + lc);
      Bs[lc + 0][r] = v.x; Bs[lc + 1][r] = v.y; Bs[lc + 2][r] = v.z; Bs[lc + 3][r] = v.w;
    }
    __syncthreads();
#pragma unroll
    for (int kk = 0; kk < BKs; ++kk) {
      float a[8], b[8];
      *(float4*)&a[0] = *(const float4*)&As[kk][ty * 8];
      *(float4*)&a[4] = *(const float4*)&As[kk][ty * 8 + 4];
      *(float4*)&b[0] = *(const float4*)&Bs[kk][tx * 8];
      *(float4*)&b[4] = *(const float4*)&Bs[kk][tx * 8 + 4];
#pragma unroll
      for (int i = 0; i < 8; ++i)
#pragma unroll
        for (int j = 0; j < 8; ++j)
          acc[i][j] = fmaf(a[i], b[j], acc[i][j]);
    }
    __syncthreads();
  }
#pragma unroll
  for (int i = 0; i < 8; ++i) {
    const int r = me + ty * 8 + i;
    if (r < cnt) {
#pragma unroll
      for (int j = 0; j < 8; ++j) {
        const int col = n0 + tx * 8 + j;
        Hb[(size_t)(off + r) * H_ + col] = fmaxf(acc[i][j] + bias[col], 0.f);
      }
    }
  }
}

// ---------------- MoE expert fc2: Yb[slot,:] = Hb[slot,:] @ ew2[e]^T + eb2[e] ----------------
__global__ __launch_bounds__(THREADS)
void moe_fc2(const float* __restrict__ Hb, const float* __restrict__ ew2,
             const float* __restrict__ eb2, float* __restrict__ Yb,
             const int* __restrict__ offs, const int* __restrict__ counts) {
  __shared__ float As[BKs][BM];
  __shared__ float Bs[BKs][BN];
  const int e = blockIdx.x >> 5;
  const int me = (blockIdx.x & 31) * BM;
  const int cnt = counts[e], off = offs[e];
  if (me >= cnt) return;
  const int n0 = blockIdx.y * BN;
  const float* Bm = ew2 + (size_t)e * D_ * H_;
  const float* bias = eb2 + (size_t)e * D_;
  const int tid = threadIdx.x;
  const int tx = tid & 15, ty = tid >> 4;
  const int lr = tid >> 2, lc = (tid & 3) * 4;
  float acc[8][8] = {};
  for (int k0 = 0; k0 < H_; k0 += BKs) {
#pragma unroll
    for (int p = 0; p < 2; ++p) {
      const int r = lr + p * 64;
      // rows beyond cnt read garbage (in-bounds of allocation) and are never stored
      const float4 v = *(const float4*)(Hb + (size_t)(off + me + r) * H_ + k0 + lc);
      As[lc + 0][r] = v.x; As[lc + 1][r] = v.y; As[lc + 2][r] = v.z; As[lc + 3][r] = v.w;
    }
#pragma unroll
    for (int p = 0; p < 2; ++p) {
      const int r = lr + p * 64;
      const float4 v = *(const float4*)(Bm + (size_t)(n0 + r) * H_ + k0 + lc);
      Bs[lc + 0][r] = v.x; Bs[lc + 1][r] = v.y; Bs[lc + 2][r] = v.z; Bs[lc + 3][r] = v.w;
    }
    __syncthreads();
#pragma unroll
    for (int kk = 0; kk < BKs; ++kk) {
      float a[8], b[8];
      *(float4*)&a[0] = *(const float4*)&As[kk][ty * 8];
      *(float4*)&a[4] = *(const float4*)&As[kk][ty * 8 + 4];
      *(float4*)&b[0] = *(const float4*)&Bs[kk][tx * 8];
      *(float4*)&b[4] = *(const float4*)&Bs[kk][tx * 8 + 4];
#pragma unroll
      for (int i = 0; i < 8; ++i)
#pragma unroll
        for (int j = 0; j < 8; ++j)
          acc[i][j] = fmaf(a[i], b[j], acc[i][j]);
    }
    __syncthreads();
  }
#pragma unroll
  for (int i = 0; i < 8; ++i) {
    const int r = me + ty * 8 + i;
    if (r < cnt) {
#pragma unroll
      for (int j = 0; j < 8; ++j) {
        const int col = n0 + tx * 8 + j;
        Yb[(size_t)(off + r) * D_ + col] = acc[i][j] + bias[col];
      }
    }
  }
}

// ---------------- x[b,:] = w0 * Yb[p0,:] + w1 * Yb[p1,:] ----------------
__global__ __launch_bounds__(256)
void moe_combine(const float* __restrict__ Yb, const int* __restrict__ slotpos,
                 const float* __restrict__ topk_w, float* __restrict__ X) {
  const int i = blockIdx.x * 256 + threadIdx.x;   // over B*D/4
  const int b = i >> 8;                            // 256 float4 per row
  const int d4 = (i & 255) * 4;
  const int p0 = slotpos[2 * b], p1 = slotpos[2 * b + 1];
  const float w0 = topk_w[2 * b], w1 = topk_w[2 * b + 1];
  const float4 a = *(const float4*)(Yb + (size_t)p0 * D_ + d4);
  const float4 c = *(const float4*)(Yb + (size_t)p1 * D_ + d4);
  float4 o;
  o.x = w0 * a.x + w1 * c.x; o.y = w0 * a.y + w1 * c.y;
  o.z = w0 * a.z + w1 * c.z; o.w = w0 * a.w + w1 * c.w;
  *(float4*)(X + (size_t)b * D_ + d4) = o;
}

// ---------------- row softmax over N columns (in place) ----------------
__global__ __launch_bounds__(256)
void softmax_rows(float* __restrict__ S, int N) {
  const int b = blockIdx.x;
  float* row = S + (size_t)b * N;
  const int tid = threadIdx.x;
  __shared__ float sm[4], ss[4];
  float mx = -3.4e38f;
  for (int i = tid; i < N; i += 256) mx = fmaxf(mx, row[i]);
#pragma unroll
  for (int o = 32; o > 0; o >>= 1) mx = fmaxf(mx, __shfl_down(mx, o));
  if ((tid & 63) == 0) sm[tid >> 6] = mx;
  __syncthreads();
  mx = fmaxf(fmaxf(sm[0], sm[1]), fmaxf(sm[2], sm[3]));
  float s = 0.f;
  for (int i = tid; i < N; i += 256) { const float e = expf(row[i] - mx); row[i] = e; s += e; }
#pragma unroll
  for (int o = 32; o > 0; o >>= 1) s += __shfl_down(s, o);
  if ((tid & 63) == 0) ss[tid >> 6] = s;
  __syncthreads();
  s = ss[0] + ss[1] + ss[2] + ss[3];
  const float inv = 1.f / s;
  for (int i = tid; i < N; i += 256) row[i] *= inv;
}

// ---------------- x = x + g * t ----------------
__global__ __launch_bounds__(256)
void gmlp_combine(float* __restrict__ X, const float* __restrict__ G,
                  const float* __restrict__ T) {
  const size_t i = (size_t)(blockIdx.x * 256 + threadIdx.x) * 4;
  const float4 xv = *(const float4*)(X + i);
  const float4 gv = *(const float4*)(G + i);
  const float4 tv = *(const float4*)(T + i);
  float4 o;
  o.x = xv.x + gv.x * tv.x; o.y = xv.y + gv.y * tv.y;
  o.z = xv.z + gv.z * tv.z; o.w = xv.w + gv.w * tv.w;
  *(float4*)(X + i) = o;
}

// =======================================================================
extern "C" void kernel_launch(void* const* d_in, const int* in_sizes, int n_in,
                              void* d_out, int out_size, void* d_ws, size_t ws_size,
                              hipStream_t stream) {
  const float* z       = (const float*)d_in[0];
  const float* gate_w  = (const float*)d_in[1];
  const float* gate_b  = (const float*)d_in[2];
  const float* ew1     = (const float*)d_in[3];
  const float* eb1     = (const float*)d_in[4];
  const float* ew2     = (const float*)d_in[5];
  const float* eb2     = (const float*)d_in[6];
  const float* keys    = (const float*)d_in[7];
  const float* values  = (const float*)d_in[8];
  const float* m1_fc1_w = (const float*)d_in[9];
  const float* m1_fc1_b = (const float*)d_in[10];
  const float* m1_fc2_w = (const float*)d_in[11];
  const float* m1_fc2_b = (const float*)d_in[12];
  const float* m1_g_w   = (const float*)d_in[13];
  const float* m1_g_b   = (const float*)d_in[14];
  const float* m2_fc1_w = (const float*)d_in[15];
  const float* m2_fc1_b = (const float*)d_in[16];
  const float* m2_fc2_w = (const float*)d_in[17];
  const float* m2_fc2_b = (const float*)d_in[18];
  const float* m2_g_w   = (const float*)d_in[19];
  const float* m2_g_b   = (const float*)d_in[20];
  const float* ad_w     = (const float*)d_in[21];
  const float* ad_b     = (const float*)d_in[22];

  float* out    = (float*)d_out;
  float* x      = out;                         // [B,D] final output #1
  float* logits = out + (size_t)B_ * D_;       // [B,V] final output #2
  // Large scratch lives in the logits region (823 MB), dead before adapter GEMM.
  float* arena  = logits;
  float* h_buf  = arena;                                  // [2B, H] = 134 MB
  float* y_buf  = arena + (size_t)2 * B_ * H_;            // [2B, D] = 33.5 MB
  float* scores = arena;                                  // [B, K]  (after MoE done)
  float* hh     = arena;                                  // [B, H] gmlp hidden
  float* t_buf  = arena + (size_t)2 * B_ * H_;            // [B, D]
  float* g_buf  = arena + (size_t)2 * B_ * H_ + (size_t)B_ * D_; // [B, D]

  // Small scratch (~132 KB): use d_ws if big enough, else the tail of the
  // logits arena (dead until the final adapter GEMM, which overwrites it
  // after all readers are done).
  const size_t small_elems = 32 + 8 * (size_t)B_;
  int* wsi;
  if (ws_size >= small_elems * sizeof(int)) {
    wsi = (int*)d_ws;
  } else {
    wsi = (int*)(out + (size_t)B_ * D_ + (size_t)B_ * V_ - small_elems);
  }
  int* counts   = wsi;                   // 8
  int* offs     = wsi + 8;               // 8
  int* curs     = wsi + 16;              // 8
  int* topk_idx = wsi + 32;              // 2B
  int* rows     = wsi + 32 + 2 * B_;     // 2B
  int* slotpos  = wsi + 32 + 4 * B_;     // 2B
  float* topk_w = (float*)(wsi + 32 + 6 * B_); // 2B

  // ---- MoE gating ----
  zero8<<<1, 64, 0, stream>>>(counts);
  gate_topk<<<B_, 64, 0, stream>>>(z, gate_w, gate_b, topk_idx, topk_w, counts);
  scan8<<<1, 1, 0, stream>>>(counts, offs, curs);
  bin_fill<<<(2 * B_ + 255) / 256, 256, 0, stream>>>(topk_idx, curs, rows, slotpos);

  // ---- MoE experts (grouped by expert) ----
  moe_fc1<<<dim3(E_ * 32, H_ / BN), THREADS, 0, stream>>>(z, ew1, eb1, h_buf, rows, offs, counts);
  moe_fc2<<<dim3(E_ * 32, D_ / BN), THREADS, 0, stream>>>(h_buf, ew2, eb2, y_buf, offs, counts);
  moe_combine<<<B_ * D_ / 4 / 256, 256, 0, stream>>>(y_buf, slotpos, topk_w, x);

  // ---- KV memory: x += softmax(z @ keys^T) @ values ----
  sgemm_abt<0><<<dim3(B_ / BM, K_ / BN), THREADS, 0, stream>>>(z, keys, nullptr, scores, B_, K_, D_);
  softmax_rows<<<B_, 256, 0, stream>>>(scores, K_);
  sgemm_ab_add<<<dim3(B_ / BM, D_ / BN), THREADS, 0, stream>>>(scores, values, x, B_, D_, K_);

  // ---- gMLP block 1 ----
  sgemm_abt<2><<<dim3(B_ / BM, H_ / BN), THREADS, 0, stream>>>(x, m1_fc1_w, m1_fc1_b, hh, B_, H_, D_);
  sgemm_abt<0><<<dim3(B_ / BM, D_ / BN), THREADS, 0, stream>>>(hh, m1_fc2_w, m1_fc2_b, t_buf, B_, D_, H_);
  sgemm_abt<3><<<dim3(B_ / BM, D_ / BN), THREADS, 0, stream>>>(x, m1_g_w, m1_g_b, g_buf, B_, D_, D_);
  gmlp_combine<<<B_ * D_ / 1024, 256, 0, stream>>>(x, g_buf, t_buf);

  // ---- gMLP block 2 ----
  sgemm_abt<2><<<dim3(B_ / BM, H_ / BN), THREADS, 0, stream>>>(x, m2_fc1_w, m2_fc1_b, hh, B_, H_, D_);
  sgemm_abt<0><<<dim3(B_ / BM, D_ / BN), THREADS, 0, stream>>>(hh, m2_fc2_w, m2_fc2_b, t_buf, B_, D_, H_);
  sgemm_abt<3><<<dim3(B_ / BM, D_ / BN), THREADS, 0, stream>>>(x, m2_g_w, m2_g_b, g_buf, B_, D_, D_);
  gmlp_combine<<<B_ * D_ / 1024, 256, 0, stream>>>(x, g_buf, t_buf);

  // ---- adapter: logits = x @ ad_w^T + ad_b (overwrites scratch region last) ----
  sgemm_abt<0><<<dim3(B_ / BM, (V_ + BN - 1) / BN), THREADS, 0, stream>>>(x, ad_w, ad_b, logits, B_, V_, D_);
}

// Round 4
// 7820.622 us; speedup vs baseline: 1.9731x; 1.9731x over previous
//
#include <hip/hip_runtime.h>
#include <math.h>

// Problem constants (fixed by the reference)
constexpr int B_ = 4096, D_ = 1024, H_ = 4096, E_ = 8, K_ = 4096, V_ = 50257;

typedef __attribute__((ext_vector_type(8))) short  short8;   // 8 bf16 (4 VGPR)
typedef __attribute__((ext_vector_type(4))) float  f32x4;    // MFMA acc

// ---------------- activations ----------------
template<int ACT> __device__ __forceinline__ float act_fn(float x) {
  if constexpr (ACT == 1) return fmaxf(x, 0.0f);                                    // relu
  if constexpr (ACT == 2) return 0.5f * x * (1.0f + erff(x * 0.7071067811865475f)); // exact gelu
  if constexpr (ACT == 3) return 1.0f / (1.0f + expf(-x));                          // sigmoid
  return x;
}

// ---------------- fp32 -> bf16 hi/lo split (x ~= hi + lo, rel err ~2^-17) ----
__device__ __forceinline__ void split1(float x, unsigned short& h, unsigned short& l) {
  unsigned int b  = __float_as_uint(x);
  unsigned int hb = (b + 0x7FFFu + ((b >> 16) & 1u)) & 0xFFFF0000u;  // RTN-even
  h = (unsigned short)(hb >> 16);
  float r = x - __uint_as_float(hb);
  unsigned int rb = __float_as_uint(r);
  l = (unsigned short)((rb + 0x7FFFu + ((rb >> 16) & 1u)) >> 16);
}

// =======================================================================
// Split-bf16 MFMA GEMM: C = act(A @ W^T + bias)   (A[M,K], W[N,K] row-major)
// 128x128 tile, BK=32, 256 thr = 4 waves, each wave a 64x64 subtile (4x4
// frags of 16x16x32 MFMA). fp32 operands are converted to (hi,lo) bf16
// during LDS staging; 3 MFMAs per frag-pair: AhBh + AhBl + AlBh.
// EP: 0 = store act(acc+bias); 1 = C += acc (no bias/act).
// GROUPED: MoE (blockIdx.x = e*nmb + mblk, guard by counts/offs).
// GATHER: A rows indirected through rowsIdx (grouped fc1).
// RAGN: ragged N (adapter): clamp W-row loads, guard col stores.
// =======================================================================
template<int ACT, int EP, bool GATHER, bool GROUPED, bool RAGN>
__global__ __launch_bounds__(256, 2)
void mgemm(const float* __restrict__ A, const float* __restrict__ W,
           const float* __restrict__ bias, float* __restrict__ C,
           int N, int K,
           const int* __restrict__ rowsIdx, const int* __restrict__ offs,
           const int* __restrict__ counts, int nmb) {
  const int tid = threadIdx.x;
  int cnt = 0, off = 0, m0;
  const int n0 = blockIdx.y * 128;
  if constexpr (GROUPED) {
    const int e  = blockIdx.x / nmb;
    const int mb = blockIdx.x % nmb;
    cnt = counts[e]; off = offs[e];
    m0 = mb * 128;
    if (m0 >= cnt) return;
    W += (size_t)e * N * K;
    if (bias) bias += (size_t)e * N;
  } else {
    m0 = blockIdx.x * 128;
  }

  __shared__ unsigned short Ah[128][32], Al[128][32], Bh[128][32], Bl[128][32];

  // staging geometry: pass p covers linear q = tid + p*256; row = q>>3,
  // float4-chunk = tid&7 (k-cols (tid&7)*4 .. +3). 4 passes per tile.
  const int cc = (tid & 7) * 4;
  int arows[4], brows[4];
#pragma unroll
  for (int p = 0; p < 4; ++p) {
    const int r = (tid >> 3) + p * 32;
    if constexpr (GROUPED) {
      if constexpr (GATHER) arows[p] = rowsIdx[off + min(m0 + r, cnt - 1)];
      else                  arows[p] = off + m0 + r;   // padded arena rows safe
    } else arows[p] = m0 + r;
    int wr_ = n0 + r;
    if constexpr (RAGN) wr_ = min(wr_, N - 1);
    brows[p] = wr_;
  }

  const int lane = tid & 63;
  const int wid  = tid >> 6;
  const int wr = (wid >> 1) * 64, wc = (wid & 1) * 64;
  const int lm = lane & 15, g = lane >> 4;

  f32x4 acc[4][4] = {};

  for (int k0 = 0; k0 < K; k0 += 32) {
    float4 va[4], vb[4];
#pragma unroll
    for (int p = 0; p < 4; ++p) {
      va[p] = *(const float4*)(A + (size_t)arows[p] * K + k0 + cc);
      vb[p] = *(const float4*)(W + (size_t)brows[p] * K + k0 + cc);
    }
#pragma unroll
    for (int p = 0; p < 4; ++p) {
      const int r = (tid >> 3) + p * 32;
      ushort4 h4, l4;
      split1(va[p].x, h4.x, l4.x); split1(va[p].y, h4.y, l4.y);
      split1(va[p].z, h4.z, l4.z); split1(va[p].w, h4.w, l4.w);
      *(ushort4*)&Ah[r][cc] = h4; *(ushort4*)&Al[r][cc] = l4;
      split1(vb[p].x, h4.x, l4.x); split1(vb[p].y, h4.y, l4.y);
      split1(vb[p].z, h4.z, l4.z); split1(vb[p].w, h4.w, l4.w);
      *(ushort4*)&Bh[r][cc] = h4; *(ushort4*)&Bl[r][cc] = l4;
    }
    __syncthreads();
    short8 bhf[4], blf[4];
#pragma unroll
    for (int n = 0; n < 4; ++n) {
      bhf[n] = *(const short8*)&Bh[wc + n * 16 + lm][g * 8];
      blf[n] = *(const short8*)&Bl[wc + n * 16 + lm][g * 8];
    }
#pragma unroll
    for (int i = 0; i < 4; ++i) {
      const short8 ahf = *(const short8*)&Ah[wr + i * 16 + lm][g * 8];
      const short8 alf = *(const short8*)&Al[wr + i * 16 + lm][g * 8];
#pragma unroll
      for (int n = 0; n < 4; ++n) {
        acc[i][n] = __builtin_amdgcn_mfma_f32_16x16x32_bf16(ahf, bhf[n], acc[i][n], 0, 0, 0);
        acc[i][n] = __builtin_amdgcn_mfma_f32_16x16x32_bf16(ahf, blf[n], acc[i][n], 0, 0, 0);
        acc[i][n] = __builtin_amdgcn_mfma_f32_16x16x32_bf16(alf, bhf[n], acc[i][n], 0, 0, 0);
      }
    }
    __syncthreads();
  }

  // epilogue: C/D layout col = lane&15, row = (lane>>4)*4 + reg  [m89-verified]
#pragma unroll
  for (int n = 0; n < 4; ++n) {
    const int col = n0 + wc + n * 16 + lm;
    if constexpr (RAGN) { if (col >= N) continue; }
    const float bv = (EP == 0 && bias != nullptr) ? bias[col] : 0.f;
#pragma unroll
    for (int i = 0; i < 4; ++i) {
#pragma unroll
      for (int rr = 0; rr < 4; ++rr) {
        const int mrow = wr + i * 16 + g * 4 + rr;
        if constexpr (GROUPED) { if (m0 + mrow >= cnt) continue; }
        const size_t crow = (GROUPED ? (size_t)off : (size_t)0) + m0 + mrow;
        if constexpr (EP == 1) C[crow * (size_t)N + col] += acc[i][n][rr];
        else                   C[crow * (size_t)N + col] = act_fn<ACT>(acc[i][n][rr] + bv);
      }
    }
  }
}

// ---------------- MoE: gate + softmax + top2 (exact fp32) ----------------
__global__ __launch_bounds__(64)
void gate_topk(const float* __restrict__ Z, const float* __restrict__ gw,
               const float* __restrict__ gb, int* __restrict__ topk_idx,
               float* __restrict__ topk_w, int* __restrict__ counts) {
  const int b = blockIdx.x, lane = threadIdx.x;
  const float* zr = Z + (size_t)b * D_;
  float l[E_];
#pragma unroll
  for (int e = 0; e < E_; ++e) {
    float s = 0.f;
    for (int d = lane; d < D_; d += 64) s += zr[d] * gw[e * D_ + d];
#pragma unroll
    for (int o = 32; o > 0; o >>= 1) s += __shfl_down(s, o);
    l[e] = s;
  }
  if (lane == 0) {
    float mx = -3.4e38f;
#pragma unroll
    for (int e = 0; e < E_; ++e) { l[e] += gb[e]; mx = fmaxf(mx, l[e]); }
    float w[E_]; float sum = 0.f;
#pragma unroll
    for (int e = 0; e < E_; ++e) { w[e] = expf(l[e] - mx); sum += w[e]; }
    const float inv = 1.f / sum;
#pragma unroll
    for (int e = 0; e < E_; ++e) w[e] *= inv;
    int i0 = 0;
#pragma unroll
    for (int e = 1; e < E_; ++e) if (w[e] > w[i0]) i0 = e;   // earliest on tie
    int i1 = (i0 == 0) ? 1 : 0;
#pragma unroll
    for (int e = 0; e < E_; ++e) if (e != i0 && w[e] > w[i1]) i1 = e;
    topk_idx[2 * b] = i0; topk_idx[2 * b + 1] = i1;
    topk_w[2 * b] = w[i0]; topk_w[2 * b + 1] = w[i1];
    atomicAdd(&counts[i0], 1); atomicAdd(&counts[i1], 1);
  }
}

__global__ void zero8(int* c) { if (threadIdx.x < 8) c[threadIdx.x] = 0; }

__global__ void scan8(const int* __restrict__ counts, int* __restrict__ offs,
                      int* __restrict__ curs) {
  if (threadIdx.x == 0 && blockIdx.x == 0) {
    int a = 0;
    for (int e = 0; e < E_; ++e) { offs[e] = a; curs[e] = a; a += counts[e]; }
  }
}

__global__ void bin_fill(const int* __restrict__ topk_idx, int* __restrict__ curs,
                         int* __restrict__ rows, int* __restrict__ slotpos) {
  const int t = blockIdx.x * blockDim.x + threadIdx.x;
  if (t < 2 * B_) {
    const int e = topk_idx[t];
    const int pos = atomicAdd(&curs[e], 1);
    rows[pos] = t >> 1;
    slotpos[t] = pos;
  }
}

// ---------------- x[b,:] = w0 * Yb[p0,:] + w1 * Yb[p1,:] ----------------
__global__ __launch_bounds__(256)
void moe_combine(const float* __restrict__ Yb, const int* __restrict__ slotpos,
                 const float* __restrict__ topk_w, float* __restrict__ X) {
  const int i = blockIdx.x * 256 + threadIdx.x;   // over B*D/4
  const int b = i >> 8;
  const int d4 = (i & 255) * 4;
  const int p0 = slotpos[2 * b], p1 = slotpos[2 * b + 1];
  const float w0 = topk_w[2 * b], w1 = topk_w[2 * b + 1];
  const float4 a = *(const float4*)(Yb + (size_t)p0 * D_ + d4);
  const float4 c = *(const float4*)(Yb + (size_t)p1 * D_ + d4);
  float4 o;
  o.x = w0 * a.x + w1 * c.x; o.y = w0 * a.y + w1 * c.y;
  o.z = w0 * a.z + w1 * c.z; o.w = w0 * a.w + w1 * c.w;
  *(float4*)(X + (size_t)b * D_ + d4) = o;
}

// ---------------- row softmax (in place) ----------------
__global__ __launch_bounds__(256)
void softmax_rows(float* __restrict__ S, int N) {
  const int b = blockIdx.x;
  float* row = S + (size_t)b * N;
  const int tid = threadIdx.x;
  __shared__ float sm[4], ss[4];
  float mx = -3.4e38f;
  for (int i = tid; i < N; i += 256) mx = fmaxf(mx, row[i]);
#pragma unroll
  for (int o = 32; o > 0; o >>= 1) mx = fmaxf(mx, __shfl_down(mx, o));
  if ((tid & 63) == 0) sm[tid >> 6] = mx;
  __syncthreads();
  mx = fmaxf(fmaxf(sm[0], sm[1]), fmaxf(sm[2], sm[3]));
  float s = 0.f;
  for (int i = tid; i < N; i += 256) { const float e = expf(row[i] - mx); row[i] = e; s += e; }
#pragma unroll
  for (int o = 32; o > 0; o >>= 1) s += __shfl_down(s, o);
  if ((tid & 63) == 0) ss[tid >> 6] = s;
  __syncthreads();
  s = ss[0] + ss[1] + ss[2] + ss[3];
  const float inv = 1.f / s;
  for (int i = tid; i < N; i += 256) row[i] *= inv;
}

// ---------------- x = x + g * t ----------------
__global__ __launch_bounds__(256)
void gmlp_combine(float* __restrict__ X, const float* __restrict__ G,
                  const float* __restrict__ T) {
  const size_t i = (size_t)(blockIdx.x * 256 + threadIdx.x) * 4;
  const float4 xv = *(const float4*)(X + i);
  const float4 gv = *(const float4*)(G + i);
  const float4 tv = *(const float4*)(T + i);
  float4 o;
  o.x = xv.x + gv.x * tv.x; o.y = xv.y + gv.y * tv.y;
  o.z = xv.z + gv.z * tv.z; o.w = xv.w + gv.w * tv.w;
  *(float4*)(X + i) = o;
}

// ---------------- values [K][D] -> vt [D][K] ----------------
__global__ void transpose_f32(const float* __restrict__ in, float* __restrict__ out) {
  __shared__ float sm[32][33];
  const int c0 = blockIdx.x * 32, r0 = blockIdx.y * 32;
  const int tx = threadIdx.x, ty = threadIdx.y;
#pragma unroll
  for (int i = 0; i < 4; ++i)
    sm[ty + i * 8][tx] = in[(size_t)(r0 + ty + i * 8) * D_ + c0 + tx];
  __syncthreads();
#pragma unroll
  for (int i = 0; i < 4; ++i)
    out[(size_t)(c0 + ty + i * 8) * K_ + r0 + tx] = sm[tx][ty + i * 8];
}

// =======================================================================
extern "C" void kernel_launch(void* const* d_in, const int* in_sizes, int n_in,
                              void* d_out, int out_size, void* d_ws, size_t ws_size,
                              hipStream_t stream) {
  const float* z       = (const float*)d_in[0];
  const float* gate_w  = (const float*)d_in[1];
  const float* gate_b  = (const float*)d_in[2];
  const float* ew1     = (const float*)d_in[3];
  const float* eb1     = (const float*)d_in[4];
  const float* ew2     = (const float*)d_in[5];
  const float* eb2     = (const float*)d_in[6];
  const float* keys    = (const float*)d_in[7];
  const float* values  = (const float*)d_in[8];
  const float* m1_fc1_w = (const float*)d_in[9];
  const float* m1_fc1_b = (const float*)d_in[10];
  const float* m1_fc2_w = (const float*)d_in[11];
  const float* m1_fc2_b = (const float*)d_in[12];
  const float* m1_g_w   = (const float*)d_in[13];
  const float* m1_g_b   = (const float*)d_in[14];
  const float* m2_fc1_w = (const float*)d_in[15];
  const float* m2_fc1_b = (const float*)d_in[16];
  const float* m2_fc2_w = (const float*)d_in[17];
  const float* m2_fc2_b = (const float*)d_in[18];
  const float* m2_g_w   = (const float*)d_in[19];
  const float* m2_g_b   = (const float*)d_in[20];
  const float* ad_w     = (const float*)d_in[21];
  const float* ad_b     = (const float*)d_in[22];

  float* out    = (float*)d_out;
  float* x      = out;                         // [B,D] final output #1
  float* logits = out + (size_t)B_ * D_;       // [B,V] final output #2

  // ---- scratch in the logits arena (dead until adapter GEMM) ----
  float* arena  = logits;
  float* Hb     = arena;                            // [8320,4096] (padded slots)
  float* Yb     = arena + 34078720ull;              // [8320,1024]
  float* vt     = arena + 42598400ull;              // [1024,4096]
  float* scores = arena;                            // [4096,4096] (after MoE)
  float* hh     = arena;                            // [4096,4096] (after KV)
  float* t_buf  = arena + 16777216ull;              // [4096,1024]
  float* g_buf  = arena + 20971520ull;              // [4096,1024]

  // Small int scratch (~132 KB): d_ws if big enough, else arena tail.
  const size_t small_elems = 32 + 8 * (size_t)B_;
  int* wsi;
  if (ws_size >= small_elems * sizeof(int)) {
    wsi = (int*)d_ws;
  } else {
    wsi = (int*)(out + (size_t)B_ * D_ + (size_t)B_ * V_ - small_elems);
  }
  int* counts   = wsi;
  int* offs     = wsi + 8;
  int* curs     = wsi + 16;
  int* topk_idx = wsi + 32;
  int* rows     = wsi + 32 + 2 * B_;
  int* slotpos  = wsi + 32 + 4 * B_;
  float* topk_w = (float*)(wsi + 32 + 6 * B_);

  // ---- MoE gating (exact fp32) ----
  zero8<<<1, 64, 0, stream>>>(counts);
  gate_topk<<<B_, 64, 0, stream>>>(z, gate_w, gate_b, topk_idx, topk_w, counts);
  scan8<<<1, 1, 0, stream>>>(counts, offs, curs);
  bin_fill<<<(2 * B_ + 255) / 256, 256, 0, stream>>>(topk_idx, curs, rows, slotpos);

  // ---- MoE experts (grouped, split-bf16 MFMA) ----
  mgemm<1, 0, true,  true,  false><<<dim3(E_ * 32, H_ / 128), 256, 0, stream>>>(
      z, ew1, eb1, Hb, H_, D_, rows, offs, counts, 32);
  mgemm<0, 0, false, true,  false><<<dim3(E_ * 32, D_ / 128), 256, 0, stream>>>(
      Hb, ew2, eb2, Yb, D_, H_, nullptr, offs, counts, 32);
  moe_combine<<<B_ * D_ / 1024, 256, 0, stream>>>(Yb, slotpos, topk_w, x);

  // ---- KV memory: x += softmax(z @ keys^T) @ values ----
  mgemm<0, 0, false, false, false><<<dim3(B_ / 128, K_ / 128), 256, 0, stream>>>(
      z, keys, nullptr, scores, K_, D_, nullptr, nullptr, nullptr, 0);
  softmax_rows<<<B_, 256, 0, stream>>>(scores, K_);
  transpose_f32<<<dim3(D_ / 32, K_ / 32), dim3(32, 8), 0, stream>>>(values, vt);
  mgemm<0, 1, false, false, false><<<dim3(B_ / 128, D_ / 128), 256, 0, stream>>>(
      scores, vt, nullptr, x, D_, K_, nullptr, nullptr, nullptr, 0);

  // ---- gMLP block 1 ----
  mgemm<2, 0, false, false, false><<<dim3(B_ / 128, H_ / 128), 256, 0, stream>>>(
      x, m1_fc1_w, m1_fc1_b, hh, H_, D_, nullptr, nullptr, nullptr, 0);
  mgemm<0, 0, false, false, false><<<dim3(B_ / 128, D_ / 128), 256, 0, stream>>>(
      hh, m1_fc2_w, m1_fc2_b, t_buf, D_, H_, nullptr, nullptr, nullptr, 0);
  mgemm<3, 0, false, false, false><<<dim3(B_ / 128, D_ / 128), 256, 0, stream>>>(
      x, m1_g_w, m1_g_b, g_buf, D_, D_, nullptr, nullptr, nullptr, 0);
  gmlp_combine<<<B_ * D_ / 1024, 256, 0, stream>>>(x, g_buf, t_buf);

  // ---- gMLP block 2 ----
  mgemm<2, 0, false, false, false><<<dim3(B_ / 128, H_ / 128), 256, 0, stream>>>(
      x, m2_fc1_w, m2_fc1_b, hh, H_, D_, nullptr, nullptr, nullptr, 0);
  mgemm<0, 0, false, false, false><<<dim3(B_ / 128, D_ / 128), 256, 0, stream>>>(
      hh, m2_fc2_w, m2_fc2_b, t_buf, D_, H_, nullptr, nullptr, nullptr, 0);
  mgemm<3, 0, false, false, false><<<dim3(B_ / 128, D_ / 128), 256, 0, stream>>>(
      x, m2_g_w, m2_g_b, g_buf, D_, D_, nullptr, nullptr, nullptr, 0);
  gmlp_combine<<<B_ * D_ / 1024, 256, 0, stream>>>(x, g_buf, t_buf);

  // ---- adapter: logits = x @ ad_w^T + ad_b (ragged N) ----
  mgemm<0, 0, false, false, true><<<dim3(B_ / 128, (V_ + 127) / 128), 256, 0, stream>>>(
      x, ad_w, ad_b, logits, V_, D_, nullptr, nullptr, nullptr, 0);
}